// Round 1
// baseline (1454.681 us; speedup 1.0000x reference)
//
#include <hip/hip_runtime.h>
#include <hip/hip_bf16.h>

// Problem constants (MoEAdaptorLayer_111669150283)
#define BATCH   512
#define LSEQ    50
#define DIN     768
#define DOUT    300
#define NEXP    8
#define NTOK    (BATCH * LSEQ)      // 25600

// ---------------------------------------------------------------------------
// Kernel 1: gates[t,e] = softmax_e( sum_i x[t,i] * w_gate[i,e] )
// One wave (64 lanes) per token; 4 waves / block.
// ---------------------------------------------------------------------------
__global__ __launch_bounds__(256) void gates_kernel(
    const float* __restrict__ x, const float* __restrict__ wg,
    float* __restrict__ gates)
{
    int wave = blockIdx.x * 4 + (threadIdx.x >> 6);
    int lane = threadIdx.x & 63;
    int t = wave;                       // grid sized exactly: NTOK/4 blocks
    const float* xr = x + (size_t)t * DIN;

    float acc[NEXP];
    #pragma unroll
    for (int e = 0; e < NEXP; e++) acc[e] = 0.0f;

    for (int i = lane; i < DIN; i += 64) {
        float xv = xr[i];
        const float* wr = wg + (size_t)i * NEXP;
        #pragma unroll
        for (int e = 0; e < NEXP; e++) acc[e] += xv * wr[e];
    }
    #pragma unroll
    for (int e = 0; e < NEXP; e++) {
        #pragma unroll
        for (int m = 32; m > 0; m >>= 1) acc[e] += __shfl_xor(acc[e], m, 64);
    }
    // every lane now has all 8 logits; softmax redundantly, lane 0 writes
    float mx = acc[0];
    #pragma unroll
    for (int e = 1; e < NEXP; e++) mx = fmaxf(mx, acc[e]);
    float ex[NEXP]; float s = 0.0f;
    #pragma unroll
    for (int e = 0; e < NEXP; e++) { ex[e] = __expf(acc[e] - mx); s += ex[e]; }
    float inv = 1.0f / s;
    if (lane == 0) {
        #pragma unroll
        for (int e = 0; e < NEXP; e++) gates[(size_t)t * NEXP + e] = ex[e] * inv;
    }
}

// ---------------------------------------------------------------------------
// Kernel 2: bw[l,e,o] = sum_i bias[e,l,i] * W[e,o,i]
// One wave per (l,e,o); 4 waves / block. 120000 outputs total.
// ---------------------------------------------------------------------------
__global__ __launch_bounds__(256) void bw_kernel(
    const float* __restrict__ bias, const float* __restrict__ W,
    float* __restrict__ bw)
{
    int wave = blockIdx.x * 4 + (threadIdx.x >> 6);   // grid exact: 30000 blocks
    int lane = threadIdx.x & 63;
    int l   = wave / (NEXP * DOUT);
    int rem = wave % (NEXP * DOUT);
    int e   = rem / DOUT;
    int o   = rem % DOUT;

    const float* br = bias + ((size_t)e * LSEQ + l) * DIN;
    const float* wr = W    + ((size_t)e * DOUT + o) * DIN;
    float acc = 0.0f;
    for (int i = lane; i < DIN; i += 64) acc += br[i] * wr[i];
    #pragma unroll
    for (int m = 32; m > 0; m >>= 1) acc += __shfl_xor(acc, m, 64);
    if (lane == 0) bw[((size_t)l * NEXP + e) * DOUT + o] = acc;
}

// ---------------------------------------------------------------------------
// Kernel 3: main fused GEMM + gate-weighted expert reduction.
//   Y[t, e, o] = sum_i x[t,i] * W[e,o,i]
//   out[t, o]  = sum_e gates[t,e] * (Y[t,e,o] - bw[t%L, e, o])
// Tile: TM=64 tokens x TN=128 cols (8 experts x TO=16 outputs), KT=32.
// 256 threads; each thread owns 4 tokens x 8 cols, where its 8 cols are the
// 8 experts of ONE output column -> expert reduction is thread-local.
// ---------------------------------------------------------------------------
#define TM  64
#define TO  16
#define TN  128   // NEXP * TO
#define KT  32
#define KTP 36    // +4 pad, keeps float4 alignment

__global__ __launch_bounds__(256) void moe_main_kernel(
    const float* __restrict__ x, const float* __restrict__ W,
    const float* __restrict__ gates, const float* __restrict__ bw,
    float* __restrict__ out)
{
    __shared__ float Xs[TM][KTP];    //  9216 B
    __shared__ float Wls[TN][KTP];   // 18432 B

    const int tid = threadIdx.x;
    const int t0 = blockIdx.x * TM;       // 400 token tiles, exact
    const int o0 = blockIdx.y * TO;       // 19 o-tiles (last partially guarded)

    const int cg = tid & 15;    // output column group: o = o0 + cg
    const int tg = tid >> 4;    // token group: tokens tg + 16*i, i=0..3

    const int lrow = tid >> 3;          // 0..31 staging row
    const int lk4  = (tid & 7) * 4;     // 0,4,...,28 staging k offset

    float acc[4][NEXP];
    #pragma unroll
    for (int i = 0; i < 4; i++)
        #pragma unroll
        for (int j = 0; j < NEXP; j++) acc[i][j] = 0.0f;

    for (int k0 = 0; k0 < DIN; k0 += KT) {
        // stage X tile: 64 rows x 32 floats
        #pragma unroll
        for (int r = 0; r < 2; r++) {
            int row = lrow + 32 * r;
            float4 v = *(const float4*)&x[((size_t)(t0 + row)) * DIN + k0 + lk4];
            *(float4*)&Xs[row][lk4] = v;
        }
        // stage W tile: 128 rows x 32 floats; row nl -> expert nl>>4, output o0+(nl&15)
        #pragma unroll
        for (int r = 0; r < 4; r++) {
            int nl = lrow + 32 * r;
            int e  = nl >> 4;
            int o  = o0 + (nl & 15);
            float4 v;
            if (o < DOUT)
                v = *(const float4*)&W[((size_t)e * DOUT + o) * DIN + k0 + lk4];
            else
                v = make_float4(0.f, 0.f, 0.f, 0.f);
            *(float4*)&Wls[nl][lk4] = v;
        }
        __syncthreads();

        #pragma unroll
        for (int k4 = 0; k4 < KT; k4 += 4) {
            float4 xa[4], wb[NEXP];
            #pragma unroll
            for (int i = 0; i < 4; i++)
                xa[i] = *(const float4*)&Xs[tg + 16 * i][k4];
            #pragma unroll
            for (int j = 0; j < NEXP; j++)
                wb[j] = *(const float4*)&Wls[cg + 16 * j][k4];
            #pragma unroll
            for (int i = 0; i < 4; i++)
                #pragma unroll
                for (int j = 0; j < NEXP; j++) {
                    acc[i][j] += xa[i].x * wb[j].x;
                    acc[i][j] += xa[i].y * wb[j].y;
                    acc[i][j] += xa[i].z * wb[j].z;
                    acc[i][j] += xa[i].w * wb[j].w;
                }
        }
        __syncthreads();
    }

    // epilogue: gate-weighted expert sum minus gate-weighted bias term
    const int o = o0 + cg;
    if (o < DOUT) {
        #pragma unroll
        for (int i = 0; i < 4; i++) {
            int t = t0 + tg + 16 * i;
            int l = t % LSEQ;
            float s = 0.0f;
            #pragma unroll
            for (int j = 0; j < NEXP; j++) {
                float g = gates[(size_t)t * NEXP + j];
                s += g * (acc[i][j] - bw[((size_t)l * NEXP + j) * DOUT + o]);
            }
            out[(size_t)t * DOUT + o] = s;
        }
    }
}

// ---------------------------------------------------------------------------
extern "C" void kernel_launch(void* const* d_in, const int* in_sizes, int n_in,
                              void* d_out, int out_size, void* d_ws, size_t ws_size,
                              hipStream_t stream) {
    const float* x     = (const float*)d_in[0];   // [512,50,768]
    const float* wgate = (const float*)d_in[1];   // [768,8]
    const float* ew    = (const float*)d_in[2];   // [8,300,768]
    const float* ebias = (const float*)d_in[3];   // [8,50,768]
    float* out = (float*)d_out;                   // [512,50,300]

    float* gates = (float*)d_ws;                          // NTOK*NEXP = 204800 floats
    float* bw    = gates + (size_t)NTOK * NEXP;           // LSEQ*NEXP*DOUT = 120000 floats

    gates_kernel<<<NTOK / 4, 256, 0, stream>>>(x, wgate, gates);
    bw_kernel<<<(LSEQ * NEXP * DOUT) / 4, 256, 0, stream>>>(ebias, ew, bw);

    dim3 grid(NTOK / TM, (DOUT + TO - 1) / TO);   // 400 x 19
    moe_main_kernel<<<grid, 256, 0, stream>>>(x, ew, gates, bw, out);
}

// Round 2
// 398.063 us; speedup vs baseline: 3.6544x; 3.6544x over previous
//
#include <hip/hip_runtime.h>
#include <hip/hip_bf16.h>

// Problem constants (MoEAdaptorLayer_111669150283)
#define BATCH   512
#define LSEQ    50
#define DIN     768
#define DOUT    300
#define NEXP    8
#define NTOK    (BATCH * LSEQ)      // 25600

typedef __bf16 bf16_t;
typedef __attribute__((ext_vector_type(8))) __bf16 bf16x8;
typedef __attribute__((ext_vector_type(4))) float f32x4;

// async global->LDS, 16 B per lane, dst = wave-uniform base + lane*16
#define GLDS16(g, l) __builtin_amdgcn_global_load_lds( \
    (__attribute__((address_space(1))) void*)(g), \
    (__attribute__((address_space(3))) void*)(l), 16, 0, 0)

// ---------------------------------------------------------------------------
// Kernel 1: gates[t,e] = softmax_e( sum_i x[t,i] * w_gate[i,e] )
// One wave per token; 4 waves / block. (verified round 1)
// ---------------------------------------------------------------------------
__global__ __launch_bounds__(256) void gates_kernel(
    const float* __restrict__ x, const float* __restrict__ wg,
    float* __restrict__ gates)
{
    int wave = blockIdx.x * 4 + (threadIdx.x >> 6);
    int lane = threadIdx.x & 63;
    int t = wave;
    const float* xr = x + (size_t)t * DIN;

    float acc[NEXP];
    #pragma unroll
    for (int e = 0; e < NEXP; e++) acc[e] = 0.0f;

    for (int i = lane; i < DIN; i += 64) {
        float xv = xr[i];
        const float* wr = wg + (size_t)i * NEXP;
        #pragma unroll
        for (int e = 0; e < NEXP; e++) acc[e] += xv * wr[e];
    }
    #pragma unroll
    for (int e = 0; e < NEXP; e++) {
        #pragma unroll
        for (int m = 32; m > 0; m >>= 1) acc[e] += __shfl_xor(acc[e], m, 64);
    }
    float mx = acc[0];
    #pragma unroll
    for (int e = 1; e < NEXP; e++) mx = fmaxf(mx, acc[e]);
    float ex[NEXP]; float s = 0.0f;
    #pragma unroll
    for (int e = 0; e < NEXP; e++) { ex[e] = __expf(acc[e] - mx); s += ex[e]; }
    float inv = 1.0f / s;
    if (lane == 0) {
        #pragma unroll
        for (int e = 0; e < NEXP; e++) gates[(size_t)t * NEXP + e] = ex[e] * inv;
    }
}

// ---------------------------------------------------------------------------
// Kernel 2: bw[l,e,o] = sum_i bias[e,l,i] * W[e,o,i]  (fp32, verified round 1)
// ---------------------------------------------------------------------------
__global__ __launch_bounds__(256) void bw_kernel(
    const float* __restrict__ bias, const float* __restrict__ W,
    float* __restrict__ bw)
{
    int wave = blockIdx.x * 4 + (threadIdx.x >> 6);
    int lane = threadIdx.x & 63;
    int l   = wave / (NEXP * DOUT);
    int rem = wave % (NEXP * DOUT);
    int e   = rem / DOUT;
    int o   = rem % DOUT;

    const float* br = bias + ((size_t)e * LSEQ + l) * DIN;
    const float* wr = W    + ((size_t)e * DOUT + o) * DIN;
    float acc = 0.0f;
    for (int i = lane; i < DIN; i += 64) acc += br[i] * wr[i];
    #pragma unroll
    for (int m = 32; m > 0; m >>= 1) acc += __shfl_xor(acc, m, 64);
    if (lane == 0) bw[((size_t)l * NEXP + e) * DOUT + o] = acc;
}

// ---------------------------------------------------------------------------
// Kernel 3: fp32 -> bf16 conversion (RNE), float4 -> 4x bf16 per thread
// ---------------------------------------------------------------------------
static __device__ __forceinline__ unsigned short f2bf(float f) {
    unsigned u = __float_as_uint(f);
    u = (u + 0x7fff + ((u >> 16) & 1)) >> 16;   // round-to-nearest-even
    return (unsigned short)u;
}

__global__ __launch_bounds__(256) void cvt_bf16_kernel(
    const float* __restrict__ in, unsigned short* __restrict__ out, int n4)
{
    int i = blockIdx.x * 256 + threadIdx.x;
    if (i >= n4) return;
    float4 v = ((const float4*)in)[i];
    ushort4 u;
    u.x = f2bf(v.x); u.y = f2bf(v.y); u.z = f2bf(v.z); u.w = f2bf(v.w);
    ((ushort4*)out)[i] = u;
}

// ---------------------------------------------------------------------------
// Kernel 4: MFMA main GEMM + fused gate-weighted expert reduction.
//   Y[t, e, o] = sum_i x[t,i] * W[e,o,i]   (bf16 MFMA, fp32 acc)
//   out[t, o]  = sum_e gates[t,e] * (Y - bw[t%L, e, o])
// Block tile: 128 tokens x (8 experts x 16 outputs). 4 waves; wave = 2 row-
// frags x 8 expert col-frags -> each lane holds all 8 expert values for one
// (token, output): expert reduction is lane-local.
// LDS layout XOR-swizzled at 16B-chunk granularity: chunk c of row r stored
// at position c ^ ((r>>2)&3). Implemented by permuting the per-lane *global*
// source addresses of global_load_lds (LDS side must stay linear).
// ---------------------------------------------------------------------------
#define GTM 128      // tokens per block
#define GTO 16       // outputs per block (x 8 experts = 128 cols)
#define GBK 32       // k per iteration (64 B per row)
#define GKIT (DIN / GBK)   // 24

__global__ __launch_bounds__(256) void moe_mfma_kernel(
    const bf16_t* __restrict__ xb, const bf16_t* __restrict__ wb,
    const float* __restrict__ gates, const float* __restrict__ bw,
    float* __restrict__ out)
{
    __shared__ bf16x8 XsV[GTM * GBK / 8];   // 8 KB
    __shared__ bf16x8 WsV[GTM * GBK / 8];   // 8 KB
    char* Xs = (char*)XsV;
    char* Ws = (char*)WsV;

    const int tid  = threadIdx.x;
    const int w    = tid >> 6;
    const int lane = tid & 63;
    const int t0   = blockIdx.x * GTM;
    const int o0   = blockIdx.y * GTO;

    // ---- staging addresses (per-lane global, swizzled chunk) ----
    // instr j of wave w covers tile rows 32w+16j+(lane>>2); lane fills stored
    // position p=lane&3 with content chunk c = p ^ ((lane>>4)&3).
    const int srow = 32 * w + (lane >> 2);
    const int c16  = 16 * ((lane & 3) ^ ((lane >> 4) & 3));

    const char* xg0 = (const char*)xb + (size_t)(t0 + srow) * (DIN * 2) + c16;
    const char* xg1 = xg0 + (size_t)16 * (DIN * 2);

    int nt0 = srow, nt1 = srow + 16;
    int e0 = nt0 >> 4, o_0 = o0 + (nt0 & 15); if (o_0 >= DOUT) o_0 = DOUT - 1;
    int e1 = nt1 >> 4, o_1 = o0 + (nt1 & 15); if (o_1 >= DOUT) o_1 = DOUT - 1;
    const char* wg0 = (const char*)wb + (size_t)(e0 * DOUT + o_0) * (DIN * 2) + c16;
    const char* wg1 = (const char*)wb + (size_t)(e1 * DOUT + o_1) * (DIN * 2) + c16;

    char* xl = Xs + 2048 * w;   // +1024 for instr 1
    char* wl = Ws + 2048 * w;

    // ---- fragment read offsets (swizzled) ----
    const int m = lane & 15, q = lane >> 4;
    const int swz = (m >> 2) & 3;
    const int aoff0 = 64 * (32 * w + m) + 16 * (q ^ swz);    // row-frag 0
    const int aoff1 = aoff0 + 64 * 16;                       // row-frag 1
    const int boff  = 64 * m + 16 * (q ^ swz);               // + 1024*e

    f32x4 acc[2][NEXP] = {};

    for (int it = 0; it < GKIT; ++it) {
        GLDS16(xg0, xl);
        GLDS16(xg1, xl + 1024);
        GLDS16(wg0, wl);
        GLDS16(wg1, wl + 1024);
        xg0 += 64; xg1 += 64; wg0 += 64; wg1 += 64;
        __syncthreads();   // drains vmcnt, publishes LDS

        bf16x8 a0 = *(const bf16x8*)(Xs + aoff0);
        bf16x8 a1 = *(const bf16x8*)(Xs + aoff1);
        #pragma unroll
        for (int e = 0; e < NEXP; ++e) {
            bf16x8 b = *(const bf16x8*)(Ws + boff + 1024 * e);
            acc[0][e] = __builtin_amdgcn_mfma_f32_16x16x32_bf16(a0, b, acc[0][e], 0, 0, 0);
            acc[1][e] = __builtin_amdgcn_mfma_f32_16x16x32_bf16(a1, b, acc[1][e], 0, 0, 0);
        }
        __syncthreads();   // protect LDS before next overwrite
    }

    // ---- epilogue: gate-weighted expert sum minus bias term ----
    const int o = o0 + m;
    if (o < DOUT) {
        #pragma unroll
        for (int mi = 0; mi < 2; ++mi) {
            int tb = t0 + 32 * w + 16 * mi + 4 * q;
            #pragma unroll
            for (int r = 0; r < 4; ++r) {
                int t = tb + r;
                int l = t % LSEQ;
                const float* gp = gates + (size_t)t * NEXP;
                const float* bp = bw + (size_t)l * NEXP * DOUT + o;
                float s = 0.0f;
                #pragma unroll
                for (int e = 0; e < NEXP; ++e)
                    s += gp[e] * (acc[mi][e][r] - bp[e * DOUT]);
                out[(size_t)t * DOUT + o] = s;
            }
        }
    }
}

// ---------------------------------------------------------------------------
// Fallback fp32 main kernel (verified round 1) — used only if ws too small.
// ---------------------------------------------------------------------------
#define TM  64
#define TO  16
#define KT  32
#define KTP 36

__global__ __launch_bounds__(256) void moe_main_kernel(
    const float* __restrict__ x, const float* __restrict__ W,
    const float* __restrict__ gates, const float* __restrict__ bw,
    float* __restrict__ out)
{
    __shared__ float Xs[TM][KTP];
    __shared__ float Wls[128][KTP];

    const int tid = threadIdx.x;
    const int t0 = blockIdx.x * TM;
    const int o0 = blockIdx.y * TO;

    const int cg = tid & 15;
    const int tg = tid >> 4;
    const int lrow = tid >> 3;
    const int lk4  = (tid & 7) * 4;

    float acc[4][NEXP];
    #pragma unroll
    for (int i = 0; i < 4; i++)
        #pragma unroll
        for (int j = 0; j < NEXP; j++) acc[i][j] = 0.0f;

    for (int k0 = 0; k0 < DIN; k0 += KT) {
        #pragma unroll
        for (int r = 0; r < 2; r++) {
            int row = lrow + 32 * r;
            float4 v = *(const float4*)&x[((size_t)(t0 + row)) * DIN + k0 + lk4];
            *(float4*)&Xs[row][lk4] = v;
        }
        #pragma unroll
        for (int r = 0; r < 4; r++) {
            int nl = lrow + 32 * r;
            int e  = nl >> 4;
            int o  = o0 + (nl & 15);
            float4 v;
            if (o < DOUT)
                v = *(const float4*)&W[((size_t)e * DOUT + o) * DIN + k0 + lk4];
            else
                v = make_float4(0.f, 0.f, 0.f, 0.f);
            *(float4*)&Wls[nl][lk4] = v;
        }
        __syncthreads();

        #pragma unroll
        for (int k4 = 0; k4 < KT; k4 += 4) {
            float4 xa[4], wb4[NEXP];
            #pragma unroll
            for (int i = 0; i < 4; i++)
                xa[i] = *(const float4*)&Xs[tg + 16 * i][k4];
            #pragma unroll
            for (int j = 0; j < NEXP; j++)
                wb4[j] = *(const float4*)&Wls[cg + 16 * j][k4];
            #pragma unroll
            for (int i = 0; i < 4; i++)
                #pragma unroll
                for (int j = 0; j < NEXP; j++) {
                    acc[i][j] += xa[i].x * wb4[j].x;
                    acc[i][j] += xa[i].y * wb4[j].y;
                    acc[i][j] += xa[i].z * wb4[j].z;
                    acc[i][j] += xa[i].w * wb4[j].w;
                }
        }
        __syncthreads();
    }

    const int o = o0 + cg;
    if (o < DOUT) {
        #pragma unroll
        for (int i = 0; i < 4; i++) {
            int t = t0 + tg + 16 * i;
            int l = t % LSEQ;
            float s = 0.0f;
            #pragma unroll
            for (int j = 0; j < NEXP; j++) {
                float g = gates[(size_t)t * NEXP + j];
                s += g * (acc[i][j] - bw[((size_t)l * NEXP + j) * DOUT + o]);
            }
            out[(size_t)t * DOUT + o] = s;
        }
    }
}

// ---------------------------------------------------------------------------
extern "C" void kernel_launch(void* const* d_in, const int* in_sizes, int n_in,
                              void* d_out, int out_size, void* d_ws, size_t ws_size,
                              hipStream_t stream) {
    const float* x     = (const float*)d_in[0];   // [512,50,768]
    const float* wgate = (const float*)d_in[1];   // [768,8]
    const float* ew    = (const float*)d_in[2];   // [8,300,768]
    const float* ebias = (const float*)d_in[3];   // [8,50,768]
    float* out = (float*)d_out;                   // [512,50,300]

    // ws layout: gates | bw | xb (bf16) | wb (bf16)
    const size_t n_gates = (size_t)NTOK * NEXP;           // 204800 f32
    const size_t n_bw    = (size_t)LSEQ * NEXP * DOUT;    // 120000 f32
    const size_t n_x     = (size_t)NTOK * DIN;            // 19,660,800
    const size_t n_w     = (size_t)NEXP * DOUT * DIN;     // 1,843,200

    float* gates = (float*)d_ws;
    float* bw    = gates + n_gates;
    bf16_t* xb   = (bf16_t*)(bw + n_bw);
    bf16_t* wbuf = xb + n_x;

    const size_t need = (n_gates + n_bw) * 4 + (n_x + n_w) * 2;

    gates_kernel<<<NTOK / 4, 256, 0, stream>>>(x, wgate, gates);
    bw_kernel<<<(LSEQ * NEXP * DOUT) / 4, 256, 0, stream>>>(ebias, ew, bw);

    if (ws_size >= need) {
        cvt_bf16_kernel<<<(int)(n_x / 4 + 255) / 256, 256, 0, stream>>>(
            x, (unsigned short*)xb, (int)(n_x / 4));
        cvt_bf16_kernel<<<(int)(n_w / 4 + 255) / 256, 256, 0, stream>>>(
            ew, (unsigned short*)wbuf, (int)(n_w / 4));
        dim3 grid(NTOK / GTM, (DOUT + GTO - 1) / GTO);   // 200 x 19
        moe_mfma_kernel<<<grid, 256, 0, stream>>>(xb, wbuf, gates, bw, out);
    } else {
        dim3 grid(NTOK / TM, (DOUT + TO - 1) / TO);      // 400 x 19
        moe_main_kernel<<<grid, 256, 0, stream>>>(x, ew, gates, bw, out);
    }
}